// Round 8
// baseline (305.997 us; speedup 1.0000x reference)
//
#include <hip/hip_runtime.h>

// Problem constants (match reference)
#define Vv 4
#define Bn 2
#define Cn 32
#define Hn 128
#define Wn 128
#define Dn 32
#define Gn 8
#define Nn 4
// derived
#define HW (Hn*Wn)            // 16384
#define BHW (Bn*Hn*Wn)        // 32768
#define DHW (Dn*Hn*Wn)        // 524288
#define BDHW (Bn*Dn*Hn*Wn)    // 1048576

// ---------------------------------------------------------------------------
// setup: per (v,b) P = src_proj_new @ inv(ref_proj_new) in f64, plus
// wtab[0..7]=w_reg, wtab[8+k]=u1[k]=sum_g w_enh[g,k],
// wtab[40+k]=u2[k]=sum_g w_reg[g]*w_enh[g,k]   (k = g2*N+n, 32 entries)
// ---------------------------------------------------------------------------
__global__ void setup_proj(const float* __restrict__ pm,
                           const float* __restrict__ wenh,
                           const float* __restrict__ wreg,
                           double* __restrict__ projws,
                           double* __restrict__ wtab) {
    int t = threadIdx.x;
    if (t < Gn) wtab[t] = (double)wreg[t];
    if (t < Gn * Nn) {
        double a = 0.0, c = 0.0;
        for (int g = 0; g < Gn; g++) {
            double wv = (double)wenh[g * (Gn * Nn) + t];
            a += wv;
            c += (double)wreg[g] * wv;
        }
        wtab[8 + t] = a; wtab[40 + t] = c;
    }
    if (t >= Vv * Bn) return;
    int v = t / Bn, b = t % Bn;
    // proj_matrices layout: (B, V+1, 2, 4, 4)
    const float* Eref = pm + (((size_t)b * (Vv + 1) + 0) * 2 + 0) * 16;
    const float* Kref = pm + (((size_t)b * (Vv + 1) + 0) * 2 + 1) * 16;
    const float* Esrc = pm + (((size_t)b * (Vv + 1) + (v + 1)) * 2 + 0) * 16;
    const float* Ksrc = pm + (((size_t)b * (Vv + 1) + (v + 1)) * 2 + 1) * 16;
    double R[16], S[16];
    for (int r = 0; r < 3; r++)
        for (int c = 0; c < 4; c++) {
            R[r*4+c] = (double)Kref[r*4+0]*Eref[0*4+c] + (double)Kref[r*4+1]*Eref[1*4+c] + (double)Kref[r*4+2]*Eref[2*4+c];
            S[r*4+c] = (double)Ksrc[r*4+0]*Esrc[0*4+c] + (double)Ksrc[r*4+1]*Esrc[1*4+c] + (double)Ksrc[r*4+2]*Esrc[2*4+c];
        }
    for (int c = 0; c < 4; c++) { R[12+c] = Eref[12+c]; S[12+c] = Esrc[12+c]; }
    double M[4][8];
    for (int r = 0; r < 4; r++)
        for (int c = 0; c < 4; c++) { M[r][c] = R[r*4+c]; M[r][4+c] = (r == c) ? 1.0 : 0.0; }
    for (int col = 0; col < 4; col++) {
        int piv = col; double best = fabs(M[col][col]);
        for (int r = col+1; r < 4; r++) { double a = fabs(M[r][col]); if (a > best) { best = a; piv = r; } }
        if (piv != col)
            for (int c = 0; c < 8; c++) { double tmp = M[col][c]; M[col][c] = M[piv][c]; M[piv][c] = tmp; }
        double inv = 1.0 / M[col][col];
        for (int c = 0; c < 8; c++) M[col][c] *= inv;
        for (int r = 0; r < 4; r++) if (r != col) {
            double f = M[r][col];
            for (int c = 0; c < 8; c++) M[r][c] -= f * M[col][c];
        }
    }
    double P[16];
    for (int r = 0; r < 4; r++)
        for (int c = 0; c < 4; c++) {
            double acc = 0.0;
            for (int k = 0; k < 4; k++) acc += S[r*4+k] * M[k][4+c];
            P[r*4+c] = acc;
        }
    double* o = projws + t * 12;
    o[0]=P[0];  o[1]=P[1];  o[2]=P[2];
    o[3]=P[4];  o[4]=P[5];  o[5]=P[6];
    o[6]=P[8];  o[7]=P[9];  o[8]=P[10];
    o[9]=P[3];  o[10]=P[7]; o[11]=P[11];
}

// ---------------------------------------------------------------------------
// transpose32: [32][HW] row-major -> [HW][32]. Two independent (in,out)
// pairs selected by blockIdx.y (0: in0->out0, 1: in1->out1).
// Block (32,8); each block does a 32(col) x 32(row) tile via LDS.
// ---------------------------------------------------------------------------
__global__ __launch_bounds__(256) void transpose32(
    const float* __restrict__ in0, float* __restrict__ out0,
    const float* __restrict__ in1, float* __restrict__ out1)
{
    __shared__ float tile[32][33];
    const float* in  = blockIdx.y ? in1  : in0;
    float*       out = blockIdx.y ? out1 : out0;
    int tx = threadIdx.x, ty = threadIdx.y;
    int p0 = blockIdx.x * 32;
    #pragma unroll
    for (int r = ty; r < 32; r += 8)
        tile[tx][r] = in[(size_t)r * HW + p0 + tx];
    __syncthreads();
    #pragma unroll
    for (int r = ty; r < 32; r += 8)
        out[(size_t)(p0 + r) * 32 + tx] = tile[r][tx];
}

// ---------------------------------------------------------------------------
// Pass 1 per (v,b): homography warp (f64 positions) + f32 bilinear/correlate
// on PIXEL-MAJOR features (srcT/refT: [p][c], 128B contiguous per pixel),
// then contract groups immediately:
//   ownbuf[p*32+d]        = (sum_g cor[g], sum_g wreg[g]*cor[g]) / 4
//   tapbuf[(p*4+n)*32+d]  = (sum_g u1[g,n]*cor[g], sum_g u2[g,n]*cor[g]) / 4
// Thread = p*32+d (pixel-outer) so all writes are coalesced; ref float4
// reads broadcast across the pixel's 32 d-lanes.
// ---------------------------------------------------------------------------
__global__ __launch_bounds__(256) void warp_corr(
    const float* __restrict__ srcT, const float* __restrict__ refT,
    const float* __restrict__ depthT, const double* __restrict__ projws,
    const double* __restrict__ wtab,
    float2* __restrict__ ownbuf, float2* __restrict__ tapbuf, int v, int b)
{
    __shared__ float sU1[Gn * Nn], sU2[Gn * Nn], sR[Gn];
    int lt = threadIdx.x;
    if (lt < Gn * Nn) { sU1[lt] = (float)wtab[8 + lt]; sU2[lt] = (float)wtab[40 + lt]; }
    if (lt < Gn) sR[lt] = (float)wtab[lt];
    __syncthreads();

    int tid = blockIdx.x * 256 + lt;            // = p*32 + d
    int d = tid & 31, p = tid >> 5;
    int w = p & 127, h = p >> 7;
    const double* pr = projws + (v * Bn + b) * 12;
    double depth = (double)depthT[(size_t)b * DHW + tid];   // [p][d] coalesced
    double xf = (double)w, yf = (double)h;
    double px = (pr[0]*xf + pr[1]*yf + pr[2]) * depth + pr[9];
    double py = (pr[3]*xf + pr[4]*yf + pr[5]) * depth + pr[10];
    double pz = (pr[6]*xf + pr[7]*yf + pr[8]) * depth + pr[11];
    if (pz == 0.0) pz = 1e-9;
    double gx = px / pz / 63.5 - 1.0;          // (W-1)/2 = 63.5
    double gy = py / pz / 63.5 - 1.0;
    double xs = (gx + 1.0) * 0.5 * 127.0;
    double ys = (gy + 1.0) * 0.5 * 127.0;
    double x0f = floor(xs), y0f = floor(ys);
    double wx = xs - x0f, wy = ys - y0f;
    int ix = (int)x0f, iy = (int)y0f;
    bool vx0 = (ix >= 0) && (ix < Wn), vx1 = (ix + 1 >= 0) && (ix + 1 < Wn);
    bool vy0 = (iy >= 0) && (iy < Hn), vy1 = (iy + 1 >= 0) && (iy + 1 < Hn);
    int cx0 = min(max(ix, 0), Wn-1), cx1 = min(max(ix+1, 0), Wn-1);
    int cy0 = min(max(iy, 0), Hn-1), cy1 = min(max(iy+1, 0), Hn-1);
    float a00 = (vx0 && vy0) ? (float)((1.0-wx)*(1.0-wy)) : 0.f;
    float a01 = (vx1 && vy0) ? (float)(wx*(1.0-wy))       : 0.f;
    float a10 = (vx0 && vy1) ? (float)((1.0-wx)*wy)       : 0.f;
    float a11 = (vx1 && vy1) ? (float)(wx*wy)             : 0.f;
    int o00 = cy0*Wn + cx0, o01 = cy0*Wn + cx1, o10 = cy1*Wn + cx0, o11 = cy1*Wn + cx1;
    const float4* sT4 = (const float4*)srcT;
    const float4* rT4 = (const float4*)refT + (size_t)p * 8;
    const float4* q00 = sT4 + (size_t)o00 * 8;
    const float4* q01 = sT4 + (size_t)o01 * 8;
    const float4* q10 = sT4 + (size_t)o10 * 8;
    const float4* q11 = sT4 + (size_t)o11 * 8;
    float cor[Gn];
    #pragma unroll
    for (int j = 0; j < Gn; j++) {               // one float4 = one group of 4 ch
        float4 t00 = q00[j], t01 = q01[j], t10 = q10[j], t11 = q11[j];
        float4 rr = rT4[j];
        float vx = a00*t00.x + a01*t01.x + a10*t10.x + a11*t11.x;
        float vy = a00*t00.y + a01*t01.y + a10*t10.y + a11*t11.y;
        float vz = a00*t00.z + a01*t01.z + a10*t10.z + a11*t11.z;
        float vw = a00*t00.w + a01*t01.w + a10*t10.w + a11*t11.w;
        cor[j] = ((vx*rr.x + vy*rr.y) + vz*rr.z) + vw*rr.w;
    }
    float s_own = 0.f, r_own = 0.f;
    #pragma unroll
    for (int g = 0; g < Gn; g++) { s_own += cor[g]; r_own += sR[g] * cor[g]; }
    float2 o2; o2.x = 0.25f * s_own; o2.y = 0.25f * r_own;
    ownbuf[tid] = o2;
    #pragma unroll
    for (int n = 0; n < Nn; n++) {
        float t1 = 0.f, t2 = 0.f;
        #pragma unroll
        for (int g = 0; g < Gn; g++) {
            t1 += sU1[g*Nn + n] * cor[g];
            t2 += sU2[g*Nn + n] * cor[g];
        }
        float2 t; t.x = 0.25f * t1; t.y = 0.25f * t2;
        tapbuf[((size_t)p * Nn + n) * Dn + d] = t;
    }
}

// ---------------------------------------------------------------------------
// Pass 2 per (v,b): random-grid bilinear sample of the pre-contracted
// (t1,t2) pairs (4 corners x 4 n, 8B per tap), add own (s,r), softmax over d
// (32-lane group), accumulate cwsum/wracc. MODE: 0 init, 1 accumulate,
// 2 accumulate + inline finalize (attn softmax, top-2 tie-guard argmax).
// Thread = (pixel-in-batch, d): tid = p*32 + d.
// ---------------------------------------------------------------------------
template <int MODE>
__global__ __launch_bounds__(256) void sample_enh(
    const float2* __restrict__ ownbuf, const float2* __restrict__ tapbuf,
    const float* __restrict__ grids,
    double* __restrict__ cwsum, double* __restrict__ wracc,
    float* __restrict__ out_corw, const float* __restrict__ depth_hypo,
    float* __restrict__ out, int v, int b)
{
    int tid = blockIdx.x * 256 + threadIdx.x;   // over DHW
    int d = tid & 31;
    int p = tid >> 5;                           // h*W + w (pixel within batch)
    int w = p & 127, h = p >> 7;

    float2 ow = ownbuf[tid];
    double s = (double)ow.x, r = (double)ow.y;

    const float* gb = grids + ((size_t)(v*Bn + b)) * Nn * HW * 2;
    #pragma unroll
    for (int n = 0; n < Nn; n++) {
        size_t gi = (((size_t)n * Hn + h) * Wn + w) * 2;
        double gx = (double)gb[gi], gy = (double)gb[gi + 1];
        double xs = (gx + 1.0) * 0.5 * 127.0;
        double ys = (gy + 1.0) * 0.5 * 127.0;
        double x0f = floor(xs), y0f = floor(ys);
        double wx = xs - x0f, wy = ys - y0f;
        int ix = (int)x0f, iy = (int)y0f;
        bool vx0 = (ix >= 0) && (ix < Wn), vx1 = (ix + 1 >= 0) && (ix + 1 < Wn);
        bool vy0 = (iy >= 0) && (iy < Hn), vy1 = (iy + 1 >= 0) && (iy + 1 < Hn);
        int cx0 = min(max(ix, 0), Wn-1), cx1 = min(max(ix+1, 0), Wn-1);
        int cy0 = min(max(iy, 0), Hn-1), cy1 = min(max(iy+1, 0), Hn-1);
        double a00 = (vx0 && vy0) ? (1.0-wx)*(1.0-wy) : 0.0;
        double a01 = (vx1 && vy0) ? wx*(1.0-wy)       : 0.0;
        double a10 = (vx0 && vy1) ? (1.0-wx)*wy       : 0.0;
        double a11 = (vx1 && vy1) ? wx*wy             : 0.0;
        float2 q00 = tapbuf[((size_t)(cy0*Wn + cx0) * Nn + n) * Dn + d];
        float2 q01 = tapbuf[((size_t)(cy0*Wn + cx1) * Nn + n) * Dn + d];
        float2 q10 = tapbuf[((size_t)(cy1*Wn + cx0) * Nn + n) * Dn + d];
        float2 q11 = tapbuf[((size_t)(cy1*Wn + cx1) * Nn + n) * Dn + d];
        s += a00*(double)q00.x + a01*(double)q01.x + a10*(double)q10.x + a11*(double)q11.x;
        r += a00*(double)q00.y + a01*(double)q01.y + a10*(double)q10.y + a11*(double)q11.y;
    }
    double logit = s * 0.5;                       // / ATTN_TEMP
    double m = logit;
    #pragma unroll
    for (int mask = 16; mask >= 1; mask >>= 1) m = fmax(m, __shfl_xor(m, mask));
    double e = exp(logit - m);
    double ssum = e;
    #pragma unroll
    for (int mask = 16; mask >= 1; mask >>= 1) ssum += __shfl_xor(ssum, mask);
    const double SQRTC = 5.656854249492381;       // sqrt(32)
    double cw = e / ssum / SQRTC;
    if (d == 0) out_corw[(size_t)v * BHW + (size_t)b * HW + p] = (float)(1.0 / ssum / SQRTC);

    if (MODE == 0) {
        cwsum[tid] = 1e-8 + cw;
        wracc[tid] = cw * r;
    } else if (MODE == 1) {
        cwsum[tid] += cw;
        wracc[tid] += cw * r;
    } else {
        // final view: finish accumulation in-register and finalize
        double cs = cwsum[tid] + cw;
        double wr = wracc[tid] + cw * r;
        double lg = wr / cs;
        double fm = lg;
        #pragma unroll
        for (int mask = 16; mask >= 1; mask >>= 1) fm = fmax(fm, __shfl_xor(fm, mask));
        double fe = exp(lg - fm);
        double fsum = fe;
        #pragma unroll
        for (int mask = 16; mask >= 1; mask >>= 1) fsum += __shfl_xor(fsum, mask);
        out[2*BHW + (size_t)b * DHW + (size_t)d * HW + p] = (float)(fe / fsum); // attn_weight
        // top-1 argmax (first index on ties)
        double bv = lg; int bi = d;
        #pragma unroll
        for (int mask = 16; mask >= 1; mask >>= 1) {
            double ov = __shfl_xor(bv, mask);
            int oi = __shfl_xor(bi, mask);
            if (ov > bv || (ov == bv && oi < bi)) { bv = ov; bi = oi; }
        }
        // runner-up (exclude bin bi)
        double rv = (d == bi) ? -1e300 : lg; int ri = d;
        #pragma unroll
        for (int mask = 16; mask >= 1; mask >>= 1) {
            double ov = __shfl_xor(rv, mask);
            int oi = __shfl_xor(ri, mask);
            if (ov > rv || (ov == rv && oi < ri)) { rv = ov; ri = oi; }
        }
        if (d == 0) {
            const float* dhb = depth_hypo + (size_t)b * DHW + p;   // + j*HW
            double eps = 5e-3 * (1.0 + fabs(bv));
            bool adj = (ri == bi + 1) || (ri == bi - 1);
            float dep;
            if (adj && (bv - rv) <= eps)
                dep = 0.5f * (dhb[(size_t)bi * HW] + dhb[(size_t)ri * HW]);  // tie midpoint
            else
                dep = dhb[(size_t)bi * HW];
            out[(size_t)b * HW + p] = dep;                                   // depth
            out[BHW + (size_t)b * HW + p] = (float)(1.0 / fsum);             // confidence
        }
    }
}

// ---------------------------------------------------------------------------
extern "C" void kernel_launch(void* const* d_in, const int* in_sizes, int n_in,
                              void* d_out, int out_size, void* d_ws, size_t ws_size,
                              hipStream_t stream) {
    const float* reff  = (const float*)d_in[0];  // (V,B,C,H,W)
    const float* srcf  = (const float*)d_in[1];  // (V,B,C,H,W)
    const float* pm    = (const float*)d_in[2];  // (B,V+1,2,4,4)
    const float* dh    = (const float*)d_in[3];  // (B,D,H,W)
    const float* grids = (const float*)d_in[4];  // (V,B,N,H,W,2)
    const float* wreg  = (const float*)d_in[5];  // (G,)
    const float* wenh  = (const float*)d_in[6];  // (G,G*N)
    float* out = (float*)d_out;
    // ws layout (bytes), ~36 MB total:
    //   proj f64 [0,1024) | wtab f64 [1024,1600) | pad to 2048
    //   cwsum f64 DHW (4.19MB) | wracc f64 DHW (4.19MB)
    //   ownbuf float2 DHW (4.19MB) | tapbuf float2 DHW*4 (16.8MB)
    //   srcT f32 [HW][32] (2.1MB) | refT f32 [HW][32] (2.1MB)
    //   depthT f32 [B][HW][32] (4.19MB)
    double* projws = (double*)d_ws;
    double* wtab   = (double*)((char*)d_ws + 1024);
    double* cwsum  = (double*)((char*)d_ws + 2048);
    double* wracc  = cwsum + DHW;
    float2* ownbuf = (float2*)(wracc + DHW);
    float2* tapbuf = ownbuf + DHW;
    float*  srcT   = (float*)(tapbuf + (size_t)DHW * Nn);
    float*  refT   = srcT + Cn * HW;
    float*  depthT = refT + Cn * HW;

    setup_proj<<<1, 64, 0, stream>>>(pm, wenh, wreg, projws, wtab);
    // depth [b][d][p] -> depthT [b][p][d] (both b in one launch via grid.y)
    transpose32<<<dim3(HW/32, 2), dim3(32, 8), 0, stream>>>(
        dh, depthT, dh + DHW, depthT + DHW);
    float* out_corw = out + 2*BHW + BDHW;
    for (int b = 0; b < Bn; b++) {
        for (int v = 0; v < Vv; v++) {
            const float* sslice = srcf + ((size_t)(v*Bn + b)) * Cn * HW;
            const float* rslice = reff + ((size_t)(v*Bn + b)) * Cn * HW;
            transpose32<<<dim3(HW/32, 2), dim3(32, 8), 0, stream>>>(
                sslice, srcT, rslice, refT);
            warp_corr<<<DHW / 256, 256, 0, stream>>>(srcT, refT, depthT, projws, wtab,
                                                     ownbuf, tapbuf, v, b);
            if (v == 0)
                sample_enh<0><<<DHW / 256, 256, 0, stream>>>(ownbuf, tapbuf, grids,
                                                             cwsum, wracc, out_corw, dh, out, v, b);
            else if (v < Vv - 1)
                sample_enh<1><<<DHW / 256, 256, 0, stream>>>(ownbuf, tapbuf, grids,
                                                             cwsum, wracc, out_corw, dh, out, v, b);
            else
                sample_enh<2><<<DHW / 256, 256, 0, stream>>>(ownbuf, tapbuf, grids,
                                                             cwsum, wracc, out_corw, dh, out, v, b);
        }
    }
}

// Round 9
// 231.893 us; speedup vs baseline: 1.3196x; 1.3196x over previous
//
#include <hip/hip_runtime.h>

// Problem constants (match reference)
#define Vv 4
#define Bn 2
#define Cn 32
#define Hn 128
#define Wn 128
#define Dn 32
#define Gn 8
#define Nn 4
// derived
#define HW (Hn*Wn)            // 16384
#define BHW (Bn*Hn*Wn)        // 32768
#define DHW (Dn*Hn*Wn)        // 524288
#define BDHW (Bn*Dn*Hn*Wn)    // 1048576
#define NBLK (DHW/256)        // 2048 blocks per phase

// ---------------------------------------------------------------------------
// setup: per (v,b) P = src_proj_new @ inv(ref_proj_new) in f64, plus
// wtab[0..7]=w_reg, wtab[8+k]=u1[k]=sum_g w_enh[g,k],
// wtab[40+k]=u2[k]=sum_g w_reg[g]*w_enh[g,k]   (k = g2*N+n, 32 entries)
// ---------------------------------------------------------------------------
__global__ void setup_proj(const float* __restrict__ pm,
                           const float* __restrict__ wenh,
                           const float* __restrict__ wreg,
                           double* __restrict__ projws,
                           double* __restrict__ wtab) {
    int t = threadIdx.x;
    if (t < Gn) wtab[t] = (double)wreg[t];
    if (t < Gn * Nn) {
        double a = 0.0, c = 0.0;
        for (int g = 0; g < Gn; g++) {
            double wv = (double)wenh[g * (Gn * Nn) + t];
            a += wv;
            c += (double)wreg[g] * wv;
        }
        wtab[8 + t] = a; wtab[40 + t] = c;
    }
    if (t >= Vv * Bn) return;
    int v = t / Bn, b = t % Bn;
    // proj_matrices layout: (B, V+1, 2, 4, 4)
    const float* Eref = pm + (((size_t)b * (Vv + 1) + 0) * 2 + 0) * 16;
    const float* Kref = pm + (((size_t)b * (Vv + 1) + 0) * 2 + 1) * 16;
    const float* Esrc = pm + (((size_t)b * (Vv + 1) + (v + 1)) * 2 + 0) * 16;
    const float* Ksrc = pm + (((size_t)b * (Vv + 1) + (v + 1)) * 2 + 1) * 16;
    double R[16], S[16];
    for (int r = 0; r < 3; r++)
        for (int c = 0; c < 4; c++) {
            R[r*4+c] = (double)Kref[r*4+0]*Eref[0*4+c] + (double)Kref[r*4+1]*Eref[1*4+c] + (double)Kref[r*4+2]*Eref[2*4+c];
            S[r*4+c] = (double)Ksrc[r*4+0]*Esrc[0*4+c] + (double)Ksrc[r*4+1]*Esrc[1*4+c] + (double)Ksrc[r*4+2]*Esrc[2*4+c];
        }
    for (int c = 0; c < 4; c++) { R[12+c] = Eref[12+c]; S[12+c] = Esrc[12+c]; }
    double M[4][8];
    for (int r = 0; r < 4; r++)
        for (int c = 0; c < 4; c++) { M[r][c] = R[r*4+c]; M[r][4+c] = (r == c) ? 1.0 : 0.0; }
    for (int col = 0; col < 4; col++) {
        int piv = col; double best = fabs(M[col][col]);
        for (int r = col+1; r < 4; r++) { double a = fabs(M[r][col]); if (a > best) { best = a; piv = r; } }
        if (piv != col)
            for (int c = 0; c < 8; c++) { double tmp = M[col][c]; M[col][c] = M[piv][c]; M[piv][c] = tmp; }
        double inv = 1.0 / M[col][col];
        for (int c = 0; c < 8; c++) M[col][c] *= inv;
        for (int r = 0; r < 4; r++) if (r != col) {
            double f = M[r][col];
            for (int c = 0; c < 8; c++) M[r][c] -= f * M[col][c];
        }
    }
    double P[16];
    for (int r = 0; r < 4; r++)
        for (int c = 0; c < 4; c++) {
            double acc = 0.0;
            for (int k = 0; k < 4; k++) acc += S[r*4+k] * M[k][4+c];
            P[r*4+c] = acc;
        }
    double* o = projws + t * 12;
    o[0]=P[0];  o[1]=P[1];  o[2]=P[2];
    o[3]=P[4];  o[4]=P[5];  o[5]=P[6];
    o[6]=P[8];  o[7]=P[9];  o[8]=P[10];
    o[9]=P[3];  o[10]=P[7]; o[11]=P[11];
}

// ---------------------------------------------------------------------------
// warp body: homography (f64 positions) + f32 bilinear/correlate on
// CHANNEL-MAJOR features, contract groups -> ownbuf (s,r), tapbuf (t1,t2)x4.
// tid = p*32 + d; writes coalesced in [p][n][d] / [p][d] layouts.
// ---------------------------------------------------------------------------
__device__ __forceinline__ void warp_body(
    int tid, const float* __restrict__ srcf, const float* __restrict__ reff,
    const float* __restrict__ dh, const double* __restrict__ projws,
    const float* sU1, const float* sU2, const float* sR,
    float2* __restrict__ ownbuf, float2* __restrict__ tapbuf, int v, int b)
{
    int d = tid & 31, p = tid >> 5;
    int w = p & 127, h = p >> 7;
    const double* pr = projws + (v * Bn + b) * 12;
    double depth = (double)dh[(size_t)(b * Dn + d) * HW + p];
    double xf = (double)w, yf = (double)h;
    double px = (pr[0]*xf + pr[1]*yf + pr[2]) * depth + pr[9];
    double py = (pr[3]*xf + pr[4]*yf + pr[5]) * depth + pr[10];
    double pz = (pr[6]*xf + pr[7]*yf + pr[8]) * depth + pr[11];
    if (pz == 0.0) pz = 1e-9;
    double gx = px / pz / 63.5 - 1.0;          // (W-1)/2 = 63.5
    double gy = py / pz / 63.5 - 1.0;
    double xs = (gx + 1.0) * 0.5 * 127.0;
    double ys = (gy + 1.0) * 0.5 * 127.0;
    double x0f = floor(xs), y0f = floor(ys);
    double wx = xs - x0f, wy = ys - y0f;
    int ix = (int)x0f, iy = (int)y0f;
    bool vx0 = (ix >= 0) && (ix < Wn), vx1 = (ix + 1 >= 0) && (ix + 1 < Wn);
    bool vy0 = (iy >= 0) && (iy < Hn), vy1 = (iy + 1 >= 0) && (iy + 1 < Hn);
    int cx0 = min(max(ix, 0), Wn-1), cx1 = min(max(ix+1, 0), Wn-1);
    int cy0 = min(max(iy, 0), Hn-1), cy1 = min(max(iy+1, 0), Hn-1);
    float a00 = (vx0 && vy0) ? (float)((1.0-wx)*(1.0-wy)) : 0.f;
    float a01 = (vx1 && vy0) ? (float)(wx*(1.0-wy))       : 0.f;
    float a10 = (vx0 && vy1) ? (float)((1.0-wx)*wy)       : 0.f;
    float a11 = (vx1 && vy1) ? (float)(wx*wy)             : 0.f;
    int o00 = cy0*Wn + cx0, o01 = cy0*Wn + cx1, o10 = cy1*Wn + cx0, o11 = cy1*Wn + cx1;
    const float* sb = srcf + ((size_t)(v*Bn + b)) * Cn * HW;
    const float* rb = reff + ((size_t)(v*Bn + b)) * Cn * HW + p;
    float cor[Gn];
    #pragma unroll
    for (int g = 0; g < Gn; g++) cor[g] = 0.f;
    #pragma unroll
    for (int c = 0; c < Cn; c++) {
        const float* sc = sb + c * HW;
        float val = a00*sc[o00] + a01*sc[o01] + a10*sc[o10] + a11*sc[o11];
        cor[c >> 2] += val * rb[c * HW];
    }
    float s_own = 0.f, r_own = 0.f;
    #pragma unroll
    for (int g = 0; g < Gn; g++) { s_own += cor[g]; r_own += sR[g] * cor[g]; }
    float2 o2; o2.x = 0.25f * s_own; o2.y = 0.25f * r_own;
    ownbuf[tid] = o2;
    #pragma unroll
    for (int n = 0; n < Nn; n++) {
        float t1 = 0.f, t2 = 0.f;
        #pragma unroll
        for (int g = 0; g < Gn; g++) {
            t1 += sU1[g*Nn + n] * cor[g];
            t2 += sU2[g*Nn + n] * cor[g];
        }
        float2 t; t.x = 0.25f * t1; t.y = 0.25f * t2;
        tapbuf[((size_t)p * Nn + n) * Dn + d] = t;
    }
}

// ---------------------------------------------------------------------------
// sample body: random-grid bilinear sample of pre-contracted (t1,t2) pairs
// (4 corners x 4 n, 8B/tap), add own (s,r), softmax over d (32-lane group),
// accumulate cwsum/wracc. MODE 0 init, 1 accumulate, 2 accumulate+finalize
// (attn softmax, top-2 tie-guard argmax -> depth/conf).
// ---------------------------------------------------------------------------
template <int MODE>
__device__ __forceinline__ void sample_body(
    int tid, const float2* __restrict__ ownbuf, const float2* __restrict__ tapbuf,
    const float* __restrict__ grids,
    double* __restrict__ cwsum, double* __restrict__ wracc,
    float* __restrict__ out_corw, const float* __restrict__ depth_hypo,
    float* __restrict__ out, int v, int b)
{
    int d = tid & 31;
    int p = tid >> 5;
    int w = p & 127, h = p >> 7;

    float2 ow = ownbuf[tid];
    double s = (double)ow.x, r = (double)ow.y;

    const float* gb = grids + ((size_t)(v*Bn + b)) * Nn * HW * 2;
    #pragma unroll
    for (int n = 0; n < Nn; n++) {
        size_t gi = (((size_t)n * Hn + h) * Wn + w) * 2;
        double gx = (double)gb[gi], gy = (double)gb[gi + 1];
        double xs = (gx + 1.0) * 0.5 * 127.0;
        double ys = (gy + 1.0) * 0.5 * 127.0;
        double x0f = floor(xs), y0f = floor(ys);
        double wx = xs - x0f, wy = ys - y0f;
        int ix = (int)x0f, iy = (int)y0f;
        bool vx0 = (ix >= 0) && (ix < Wn), vx1 = (ix + 1 >= 0) && (ix + 1 < Wn);
        bool vy0 = (iy >= 0) && (iy < Hn), vy1 = (iy + 1 >= 0) && (iy + 1 < Hn);
        int cx0 = min(max(ix, 0), Wn-1), cx1 = min(max(ix+1, 0), Wn-1);
        int cy0 = min(max(iy, 0), Hn-1), cy1 = min(max(iy+1, 0), Hn-1);
        double a00 = (vx0 && vy0) ? (1.0-wx)*(1.0-wy) : 0.0;
        double a01 = (vx1 && vy0) ? wx*(1.0-wy)       : 0.0;
        double a10 = (vx0 && vy1) ? (1.0-wx)*wy       : 0.0;
        double a11 = (vx1 && vy1) ? wx*wy             : 0.0;
        float2 q00 = tapbuf[((size_t)(cy0*Wn + cx0) * Nn + n) * Dn + d];
        float2 q01 = tapbuf[((size_t)(cy0*Wn + cx1) * Nn + n) * Dn + d];
        float2 q10 = tapbuf[((size_t)(cy1*Wn + cx0) * Nn + n) * Dn + d];
        float2 q11 = tapbuf[((size_t)(cy1*Wn + cx1) * Nn + n) * Dn + d];
        s += a00*(double)q00.x + a01*(double)q01.x + a10*(double)q10.x + a11*(double)q11.x;
        r += a00*(double)q00.y + a01*(double)q01.y + a10*(double)q10.y + a11*(double)q11.y;
    }
    double logit = s * 0.5;                       // / ATTN_TEMP
    double m = logit;
    #pragma unroll
    for (int mask = 16; mask >= 1; mask >>= 1) m = fmax(m, __shfl_xor(m, mask));
    double e = exp(logit - m);
    double ssum = e;
    #pragma unroll
    for (int mask = 16; mask >= 1; mask >>= 1) ssum += __shfl_xor(ssum, mask);
    const double SQRTC = 5.656854249492381;       // sqrt(32)
    double cw = e / ssum / SQRTC;
    if (d == 0) out_corw[(size_t)v * BHW + (size_t)b * HW + p] = (float)(1.0 / ssum / SQRTC);

    if (MODE == 0) {
        cwsum[tid] = 1e-8 + cw;
        wracc[tid] = cw * r;
    } else if (MODE == 1) {
        cwsum[tid] += cw;
        wracc[tid] += cw * r;
    } else {
        double cs = cwsum[tid] + cw;
        double wr = wracc[tid] + cw * r;
        double lg = wr / cs;
        double fm = lg;
        #pragma unroll
        for (int mask = 16; mask >= 1; mask >>= 1) fm = fmax(fm, __shfl_xor(fm, mask));
        double fe = exp(lg - fm);
        double fsum = fe;
        #pragma unroll
        for (int mask = 16; mask >= 1; mask >>= 1) fsum += __shfl_xor(fsum, mask);
        out[2*BHW + (size_t)b * DHW + (size_t)d * HW + p] = (float)(fe / fsum); // attn_weight
        double bv = lg; int bi = d;
        #pragma unroll
        for (int mask = 16; mask >= 1; mask >>= 1) {
            double ov = __shfl_xor(bv, mask);
            int oi = __shfl_xor(bi, mask);
            if (ov > bv || (ov == bv && oi < bi)) { bv = ov; bi = oi; }
        }
        double rv = (d == bi) ? -1e300 : lg; int ri = d;
        #pragma unroll
        for (int mask = 16; mask >= 1; mask >>= 1) {
            double ov = __shfl_xor(rv, mask);
            int oi = __shfl_xor(ri, mask);
            if (ov > rv || (ov == rv && oi < ri)) { rv = ov; ri = oi; }
        }
        if (d == 0) {
            const float* dhb = depth_hypo + (size_t)b * DHW + p;   // + j*HW
            double eps = 5e-3 * (1.0 + fabs(bv));
            bool adj = (ri == bi + 1) || (ri == bi - 1);
            float dep;
            if (adj && (bv - rv) <= eps)
                dep = 0.5f * (dhb[(size_t)bi * HW] + dhb[(size_t)ri * HW]);  // tie midpoint
            else
                dep = dhb[(size_t)bi * HW];
            out[(size_t)b * HW + p] = dep;                                   // depth
            out[BHW + (size_t)b * HW + p] = (float)(1.0 / fsum);             // confidence
        }
    }
}

// ---------------------------------------------------------------------------
// standalone kernels
// ---------------------------------------------------------------------------
__global__ __launch_bounds__(256) void warp_corr(
    const float* __restrict__ srcf, const float* __restrict__ reff,
    const float* __restrict__ dh, const double* __restrict__ projws,
    const double* __restrict__ wtab,
    float2* __restrict__ ownbuf, float2* __restrict__ tapbuf, int v, int b)
{
    __shared__ float sU1[Gn * Nn], sU2[Gn * Nn], sR[Gn];
    int lt = threadIdx.x;
    if (lt < Gn * Nn) { sU1[lt] = (float)wtab[8 + lt]; sU2[lt] = (float)wtab[40 + lt]; }
    if (lt < Gn) sR[lt] = (float)wtab[lt];
    __syncthreads();
    warp_body(blockIdx.x * 256 + lt, srcf, reff, dh, projws, sU1, sU2, sR,
              ownbuf, tapbuf, v, b);
}

template <int MODE>
__global__ __launch_bounds__(256) void sample_enh(
    const float2* __restrict__ ownbuf, const float2* __restrict__ tapbuf,
    const float* __restrict__ grids,
    double* __restrict__ cwsum, double* __restrict__ wracc,
    float* __restrict__ out_corw, const float* __restrict__ depth_hypo,
    float* __restrict__ out, int v, int b)
{
    sample_body<MODE>(blockIdx.x * 256 + threadIdx.x, ownbuf, tapbuf, grids,
                      cwsum, wracc, out_corw, depth_hypo, out, v, b);
}

// ---------------------------------------------------------------------------
// fused pipeline stage: blocks [0,NBLK) run sample(stage k-1) from (ownR,tapR);
// blocks [NBLK,2*NBLK) run warp(stage k) into (ownW,tapW). Independent halves.
// ---------------------------------------------------------------------------
template <int MODE>
__global__ __launch_bounds__(256) void fused_sw(
    const float* __restrict__ srcf, const float* __restrict__ reff,
    const float* __restrict__ dh, const double* __restrict__ projws,
    const double* __restrict__ wtab, const float* __restrict__ grids,
    const float2* __restrict__ ownR, const float2* __restrict__ tapR,
    float2* __restrict__ ownW, float2* __restrict__ tapW,
    double* __restrict__ cwsum, double* __restrict__ wracc,
    float* __restrict__ out_corw, float* __restrict__ out,
    int vs, int bs, int vw, int bw)
{
    int lt = threadIdx.x;
    if (blockIdx.x < NBLK) {
        sample_body<MODE>(blockIdx.x * 256 + lt, ownR, tapR, grids,
                          cwsum, wracc, out_corw, dh, out, vs, bs);
    } else {
        __shared__ float sU1[Gn * Nn], sU2[Gn * Nn], sR[Gn];
        if (lt < Gn * Nn) { sU1[lt] = (float)wtab[8 + lt]; sU2[lt] = (float)wtab[40 + lt]; }
        if (lt < Gn) sR[lt] = (float)wtab[lt];
        __syncthreads();
        warp_body((blockIdx.x - NBLK) * 256 + lt, srcf, reff, dh, projws,
                  sU1, sU2, sR, ownW, tapW, vw, bw);
    }
}

// ---------------------------------------------------------------------------
extern "C" void kernel_launch(void* const* d_in, const int* in_sizes, int n_in,
                              void* d_out, int out_size, void* d_ws, size_t ws_size,
                              hipStream_t stream) {
    const float* reff  = (const float*)d_in[0];  // (V,B,C,H,W)
    const float* srcf  = (const float*)d_in[1];  // (V,B,C,H,W)
    const float* pm    = (const float*)d_in[2];  // (B,V+1,2,4,4)
    const float* dh    = (const float*)d_in[3];  // (B,D,H,W)
    const float* grids = (const float*)d_in[4];  // (V,B,N,H,W,2)
    const float* wreg  = (const float*)d_in[5];  // (G,)
    const float* wenh  = (const float*)d_in[6];  // (G,G*N)
    float* out = (float*)d_out;
    // ws layout (bytes):
    //   proj f64 [0,1024) | wtab f64 [1024,1600) | pad to 2048
    //   cwsum f64 DHW | wracc f64 DHW | own0 f2 DHW | tap0 f2 4*DHW
    //   [pipelined only:] own1 f2 DHW | tap1 f2 4*DHW
    double* projws = (double*)d_ws;
    double* wtab   = (double*)((char*)d_ws + 1024);
    double* cwsum  = (double*)((char*)d_ws + 2048);
    double* wracc  = cwsum + DHW;
    float2* own0   = (float2*)(wracc + DHW);
    float2* tap0   = own0 + DHW;
    float2* own1   = tap0 + (size_t)DHW * Nn;
    float2* tap1   = own1 + DHW;
    size_t need_pipe = 2048 + (size_t)DHW * 16 + 2 * ((size_t)DHW * 8 + (size_t)DHW * Nn * 8);
    bool pipe = (ws_size >= need_pipe);

    setup_proj<<<1, 64, 0, stream>>>(pm, wenh, wreg, projws, wtab);
    float* out_corw = out + 2*BHW + BDHW;

    if (pipe) {
        // stages k = b*4 + v, k = 0..7; buffers by parity (k&1)
        float2* owns[2] = { own0, own1 };
        float2* taps[2] = { tap0, tap1 };
        // L0: warp stage 0 -> buf0
        warp_corr<<<NBLK, 256, 0, stream>>>(srcf, reff, dh, projws, wtab,
                                            own0, tap0, 0, 0);
        // L1..L7: fused sample(k-1) || warp(k)
        for (int k = 1; k < 8; k++) {
            int vs = (k - 1) & 3, bs = (k - 1) >> 2;
            int vw = k & 3,       bw = k >> 2;
            float2* oR = owns[(k - 1) & 1]; float2* tR = taps[(k - 1) & 1];
            float2* oW = owns[k & 1];       float2* tW = taps[k & 1];
            if (vs == 0)
                fused_sw<0><<<2*NBLK, 256, 0, stream>>>(srcf, reff, dh, projws, wtab, grids,
                                                        oR, tR, oW, tW, cwsum, wracc,
                                                        out_corw, out, vs, bs, vw, bw);
            else if (vs == 3)
                fused_sw<2><<<2*NBLK, 256, 0, stream>>>(srcf, reff, dh, projws, wtab, grids,
                                                        oR, tR, oW, tW, cwsum, wracc,
                                                        out_corw, out, vs, bs, vw, bw);
            else
                fused_sw<1><<<2*NBLK, 256, 0, stream>>>(srcf, reff, dh, projws, wtab, grids,
                                                        oR, tR, oW, tW, cwsum, wracc,
                                                        out_corw, out, vs, bs, vw, bw);
        }
        // L8: final sample stage 7 (b=1, v=3, MODE 2), buf parity 1
        sample_enh<2><<<NBLK, 256, 0, stream>>>(owns[1], taps[1], grids, cwsum, wracc,
                                                out_corw, dh, out, 3, 1);
    } else {
        // fallback: R7 serial structure (proven)
        for (int b = 0; b < Bn; b++) {
            for (int v = 0; v < Vv; v++) {
                warp_corr<<<NBLK, 256, 0, stream>>>(srcf, reff, dh, projws, wtab,
                                                    own0, tap0, v, b);
                if (v == 0)
                    sample_enh<0><<<NBLK, 256, 0, stream>>>(own0, tap0, grids, cwsum, wracc,
                                                            out_corw, dh, out, v, b);
                else if (v < Vv - 1)
                    sample_enh<1><<<NBLK, 256, 0, stream>>>(own0, tap0, grids, cwsum, wracc,
                                                            out_corw, dh, out, v, b);
                else
                    sample_enh<2><<<NBLK, 256, 0, stream>>>(own0, tap0, grids, cwsum, wracc,
                                                            out_corw, dh, out, v, b);
            }
        }
    }
}